// Round 3
// baseline (1078.539 us; speedup 1.0000x reference)
//
#include <hip/hip_runtime.h>

static constexpr int Wd  = 128;
static constexpr int Hd  = 128;
static constexpr int HWc = Wd * Hd;    // 16384
static constexpr int Cc  = 128;
static constexpr int NHc = 4;
static constexpr int Bc  = 2;

__device__ __forceinline__ int refl(int i, int L) {
    i = i < 0 ? -i : i;
    return i >= L ? 2 * (L - 1) - i : i;
}

// ---------------- Kernel A: depthwise 3x3 + bias + relu (zero padding) ----------------
__global__ __launch_bounds__(256) void dw_kernel(
    const float* __restrict__ vid,
    const float* __restrict__ wq, const float* __restrict__ bq,
    const float* __restrict__ wk, const float* __restrict__ bk,
    const float* __restrict__ wv, const float* __restrict__ bv,
    float* __restrict__ yq, float* __restrict__ yk, float* __restrict__ yv)
{
    int pix  = blockIdx.x * 256 + threadIdx.x;
    int bc   = blockIdx.y;           // b*C + c
    int conv = blockIdx.z;
    const float* wsel = conv == 0 ? wq : (conv == 1 ? wk : wv);
    const float* bsel = conv == 0 ? bq : (conv == 1 ? bk : bv);
    float* osel       = conv == 0 ? yq : (conv == 1 ? yk : yv);
    int c = bc & (Cc - 1);
    int y = pix >> 7, x = pix & (Wd - 1);
    const float* src = vid + (size_t)bc * HWc;
    const float* wp  = wsel + c * 9;
    float acc = 0.f;
    #pragma unroll
    for (int ky = 0; ky < 3; ++ky) {
        int iy = y + ky - 1;
        if (iy < 0 || iy >= Hd) continue;
        #pragma unroll
        for (int kx = 0; kx < 3; ++kx) {
            int ix = x + kx - 1;
            if (ix < 0 || ix >= Wd) continue;
            acc = fmaf(src[iy * Wd + ix], wp[ky * 3 + kx], acc);
        }
    }
    acc += bsel[c];
    osel[(size_t)bc * HWc + pix] = fmaxf(acc, 0.f);
}

// ---------------- Kernel B/D: pointwise GEMM, c-major in/out, in-place safe ----------
__global__ __launch_bounds__(256) void pw_kernel(
    const float* y0p, const float* y1p, const float* y2p,
    const float* __restrict__ w0,  const float* __restrict__ w1,  const float* __restrict__ w2,
    const float* __restrict__ b0,  const float* __restrict__ b1,  const float* __restrict__ b2,
    float* o0, float* o1, float* o2,
    float scale0)
{
    extern __shared__ float lds[];
    float* wl = lds;            // [64 cc][129]
    float* yl = lds + 8256;     // [64 cc][128 p]

    int z = blockIdx.z;
    const float* yin  = z == 0 ? y0p : (z == 1 ? y1p : y2p);
    const float* wmat = z == 0 ? w0  : (z == 1 ? w1  : w2);
    const float* bias = z == 0 ? b0  : (z == 1 ? b1  : b2);
    float* out        = z == 0 ? o0  : (z == 1 ? o1  : o2);
    float scale       = z == 0 ? scale0 : 1.f;

    int tid = threadIdx.x;
    int ot = tid & 15, pt = tid >> 4;
    int gp  = blockIdx.x * 128;
    int b   = gp >> 14;
    int pof = gp & (HWc - 1);
    const float* yb = yin + (size_t)b * Cc * HWc + pof;

    float acc[8][8];
    #pragma unroll
    for (int i = 0; i < 8; ++i)
        #pragma unroll
        for (int j = 0; j < 8; ++j) acc[i][j] = 0.f;

    for (int kh = 0; kh < 2; ++kh) {
        int c0 = kh * 64;
        for (int i = tid; i < 8192; i += 256) {
            int cc = i & 63, o = i >> 6;
            wl[cc * 129 + o] = wmat[o * 128 + c0 + cc];
        }
        for (int i = tid; i < 8192; i += 256) {
            int p = i & 127, cc = i >> 7;
            yl[cc * 128 + p] = yb[(size_t)(c0 + cc) * HWc + p];
        }
        __syncthreads();
        #pragma unroll 4
        for (int cc = 0; cc < 64; ++cc) {
            float wv[8], pv[8];
            #pragma unroll
            for (int oi = 0; oi < 8; ++oi) wv[oi] = wl[cc * 129 + oi * 16 + ot];
            #pragma unroll
            for (int pi = 0; pi < 8; ++pi) pv[pi] = yl[cc * 128 + pi * 16 + pt];
            #pragma unroll
            for (int oi = 0; oi < 8; ++oi)
                #pragma unroll
                for (int pi = 0; pi < 8; ++pi)
                    acc[oi][pi] = fmaf(wv[oi], pv[pi], acc[oi][pi]);
        }
        __syncthreads();
    }

    float bia[8];
    #pragma unroll
    for (int oi = 0; oi < 8; ++oi) bia[oi] = bias[oi * 16 + ot];

    #pragma unroll
    for (int oi = 0; oi < 8; ++oi)
        #pragma unroll
        for (int pi = 0; pi < 8; ++pi)
            lds[(pi * 16 + pt) * 133 + oi * 16 + ot] = (acc[oi][pi] + bia[oi]) * scale;
    __syncthreads();

    for (int i = tid; i < 16384; i += 256) {
        int p = i & 127, o = i >> 7;
        out[(size_t)b * Cc * HWc + (size_t)o * HWc + pof + p] = lds[p * 133 + o];
    }
}

// ---------------- Kernel C: neighborhood attention, split-channel ---------------------
// 512 threads: lane pair (2*pl, 2*pl+1) shares pixel pl; each handles 16 channels.
// q,k,v c-major (B,C,H,W); att in-place over q.
__global__ __launch_bounds__(512, 4) void attn_kernel(
    const float* q, const float* kk, const float* vv, float* att)
{
    extern __shared__ float lds[];   // [529 pix][36 floats] (144B pixel stride)
    int tid = threadIdx.x;
    int x0 = blockIdx.x * 16, y0 = blockIdx.y * 16;
    int bn = blockIdx.z;
    const float* kb = kk + (size_t)bn * 32 * HWc;
    const float* vb = vv + (size_t)bn * 32 * HWc;

    // ---- staging geometry: thread tid stages region pixel tid (+ tail 512..528)
    int sry = tid / 23, srx = tid - sry * 23;
    int sgo = refl(y0 - 4 + sry, Hd) * Wd + refl(x0 - 4 + srx, Wd);
    int t2 = tid + 512;
    int sry2 = t2 / 23, srx2 = t2 - sry2 * 23;
    int sgo2 = refl(y0 - 4 + sry2, Hd) * Wd + refl(x0 - 4 + srx2, Wd);
    bool tail = (tid < 529 - 512);

    // ---- compute geometry
    int half = tid & 1;            // which 16 channels
    int pl   = tid >> 1;           // pixel 0..255
    int px = pl & 15, py = pl >> 4;
    int gq = (y0 + py) * Wd + (x0 + px);
    int rbase = py * 23 + px;      // region idx of offset (dy=-4,dx=-4)
    float* myk = lds + rbase * 36 + half * 16;   // 4 quads at +0,4,8,12 floats

    // ================= stage K =================
    #pragma unroll
    for (int cbq = 0; cbq < 8; ++cbq) {
        float4 v;
        v.x = kb[(size_t)(cbq * 4 + 0) * HWc + sgo];
        v.y = kb[(size_t)(cbq * 4 + 1) * HWc + sgo];
        v.z = kb[(size_t)(cbq * 4 + 2) * HWc + sgo];
        v.w = kb[(size_t)(cbq * 4 + 3) * HWc + sgo];
        *(float4*)(lds + tid * 36 + cbq * 4) = v;
    }
    if (tail) {
        #pragma unroll
        for (int cbq = 0; cbq < 8; ++cbq) {
            float4 v;
            v.x = kb[(size_t)(cbq * 4 + 0) * HWc + sgo2];
            v.y = kb[(size_t)(cbq * 4 + 1) * HWc + sgo2];
            v.z = kb[(size_t)(cbq * 4 + 2) * HWc + sgo2];
            v.w = kb[(size_t)(cbq * 4 + 3) * HWc + sgo2];
            *(float4*)(lds + t2 * 36 + cbq * 4) = v;
        }
    }
    __syncthreads();

    // ================= QK over my 16 channels =================
    float d[64];
    #pragma unroll
    for (int i = 0; i < 64; ++i) d[i] = 0.f;
    {
        const float* qp = q + (size_t)(bn * 32 + half * 16) * HWc + gq;
        #pragma unroll
        for (int cbq = 0; cbq < 4; ++cbq) {
            float4 q4;
            q4.x = qp[(size_t)(cbq * 4 + 0) * HWc];
            q4.y = qp[(size_t)(cbq * 4 + 1) * HWc];
            q4.z = qp[(size_t)(cbq * 4 + 2) * HWc];
            q4.w = qp[(size_t)(cbq * 4 + 3) * HWc];
            #pragma unroll
            for (int off = 0; off < 64; ++off) {
                int dy = off >> 3, dx = off & 7;
                const float4 kv = *(const float4*)(myk + (dy * 23 + dx) * 36 + cbq * 4);
                d[off] = fmaf(q4.x, kv.x, fmaf(q4.y, kv.y, fmaf(q4.z, kv.z, fmaf(q4.w, kv.w, d[off]))));
            }
        }
    }
    __syncthreads();   // all QK reads done before V overwrites

    // ================= stage V (overlaps following VALU) =================
    #pragma unroll
    for (int cbq = 0; cbq < 8; ++cbq) {
        float4 v;
        v.x = vb[(size_t)(cbq * 4 + 0) * HWc + sgo];
        v.y = vb[(size_t)(cbq * 4 + 1) * HWc + sgo];
        v.z = vb[(size_t)(cbq * 4 + 2) * HWc + sgo];
        v.w = vb[(size_t)(cbq * 4 + 3) * HWc + sgo];
        *(float4*)(lds + tid * 36 + cbq * 4) = v;
    }
    if (tail) {
        #pragma unroll
        for (int cbq = 0; cbq < 8; ++cbq) {
            float4 v;
            v.x = vb[(size_t)(cbq * 4 + 0) * HWc + sgo2];
            v.y = vb[(size_t)(cbq * 4 + 1) * HWc + sgo2];
            v.z = vb[(size_t)(cbq * 4 + 2) * HWc + sgo2];
            v.w = vb[(size_t)(cbq * 4 + 3) * HWc + sgo2];
            *(float4*)(lds + t2 * 36 + cbq * 4) = v;
        }
    }

    // ---- combine channel halves (lane^1 shares the pixel) — DPP, no LDS
    #pragma unroll
    for (int i = 0; i < 64; ++i) d[i] += __shfl_xor(d[i], 1);

    // ---- top-16 ranking (lower index wins ties == lax.top_k), packed ranks
    unsigned rk[16];
    #pragma unroll
    for (int i = 0; i < 16; ++i) rk[i] = 0u;
    #pragma unroll
    for (int i = 0; i < 63; ++i) {
        #pragma unroll
        for (int j = i + 1; j < 64; ++j) {
            bool ge = d[i] >= d[j];
            rk[i >> 2] += ge ? 0u : (1u << (8 * (i & 3)));
            rk[j >> 2] += ge ? (1u << (8 * (j & 3))) : 0u;
        }
    }
    float m = d[0];
    #pragma unroll
    for (int i = 1; i < 64; ++i) m = fmaxf(m, d[i]);
    float s = 0.f;
    #pragma unroll
    for (int i = 0; i < 64; ++i) {
        unsigned r = (rk[i >> 2] >> (8 * (i & 3))) & 255u;
        float e = (r < 16u) ? __expf(d[i] - m) : 0.f;
        d[i] = e;
        s += e;
    }
    float inv = 1.0f / s;
    __syncthreads();   // V fully staged

    // ================= PV over my 16 channels =================
    float acc[16];
    #pragma unroll
    for (int c = 0; c < 16; ++c) acc[c] = 0.f;
    #pragma unroll
    for (int cbq = 0; cbq < 4; ++cbq) {
        #pragma unroll
        for (int off = 0; off < 64; ++off) {
            int dy = off >> 3, dx = off & 7;
            const float4 vv4 = *(const float4*)(myk + (dy * 23 + dx) * 36 + cbq * 4);
            float wg = d[off];
            acc[cbq*4+0] = fmaf(wg, vv4.x, acc[cbq*4+0]);
            acc[cbq*4+1] = fmaf(wg, vv4.y, acc[cbq*4+1]);
            acc[cbq*4+2] = fmaf(wg, vv4.z, acc[cbq*4+2]);
            acc[cbq*4+3] = fmaf(wg, vv4.w, acc[cbq*4+3]);
        }
    }

    float* op = att + (size_t)(bn * 32 + half * 16) * HWc + gq;
    #pragma unroll
    for (int c = 0; c < 16; ++c) op[(size_t)c * HWc] = acc[c] * inv;
}

// ---------------------------------- launcher ------------------------------------------
extern "C" void kernel_launch(void* const* d_in, const int* in_sizes, int n_in,
                              void* d_out, int out_size, void* d_ws, size_t ws_size,
                              hipStream_t stream)
{
    const float* vid  = (const float*)d_in[0];
    const float* qdww = (const float*)d_in[1];
    const float* qdwb = (const float*)d_in[2];
    const float* qpww = (const float*)d_in[3];
    const float* qpwb = (const float*)d_in[4];
    const float* kdww = (const float*)d_in[5];
    const float* kdwb = (const float*)d_in[6];
    const float* kpww = (const float*)d_in[7];
    const float* kpwb = (const float*)d_in[8];
    const float* vdww = (const float*)d_in[9];
    const float* vdwb = (const float*)d_in[10];
    const float* vpww = (const float*)d_in[11];
    const float* vpwb = (const float*)d_in[12];
    const float* pjw  = (const float*)d_in[13];
    const float* pjb  = (const float*)d_in[14];

    float* ws = (float*)d_ws;
    const size_t SZ = (size_t)Bc * Cc * HWc;   // 16 MB each
    float* buf0 = ws;            // q-dw -> q -> att
    float* buf1 = ws + SZ;       // k-dw -> k
    float* buf2 = ws + 2 * SZ;   // v-dw -> v

    hipFuncSetAttribute((const void*)pw_kernel,   hipFuncAttributeMaxDynamicSharedMemorySize, 68096);
    hipFuncSetAttribute((const void*)attn_kernel, hipFuncAttributeMaxDynamicSharedMemorySize, 76176);

    dw_kernel<<<dim3(HWc / 256, Bc * Cc, 3), 256, 0, stream>>>(
        vid, qdww, qdwb, kdww, kdwb, vdww, vdwb, buf0, buf1, buf2);

    const float scale = 0.17677669529663687f;
    pw_kernel<<<dim3((Bc * HWc) / 128, 1, 3), 256, 68096, stream>>>(
        buf0, buf1, buf2, qpww, kpww, vpww, qpwb, kpwb, vpwb, buf0, buf1, buf2, scale);

    attn_kernel<<<dim3(Wd / 16, Hd / 16, Bc * NHc), 512, 76176, stream>>>(buf0, buf1, buf2, buf0);

    pw_kernel<<<dim3((Bc * HWc) / 128, 1, 1), 256, 68096, stream>>>(
        buf0, buf0, buf0, pjw, pjw, pjw, pjb, pjb, pjb, (float*)d_out, (float*)d_out, (float*)d_out, 1.f);
}